// Round 2
// baseline (789.684 us; speedup 1.0000x reference)
//
#include <hip/hip_runtime.h>

#define N_NODES 100000
#define N_EDGES 1600000
#define D_FEAT 64

#define RB_LOG 7
#define ROWS_PER_BUCKET 128
#define N_BUCKET ((N_NODES + ROWS_PER_BUCKET - 1) / ROWS_PER_BUCKET)  // 782

#define COL_BITS 17
#define COL_MASK ((1 << COL_BITS) - 1)

#define CAP 2560       // records per bucket cell; mean 2048, sigma ~45 -> +11 sigma
#define PAD 16
#define OVF_MAX 4096

// ---------------- scatter: tile counting-sort + coalesced burst write ------
#define STILE 4096
#define STHREADS 512
#define SEPT (STILE / STHREADS)                      // 8
#define N_STILE ((N_EDGES + STILE - 1) / STILE)      // 391

__global__ __launch_bounds__(512) void scatter_kernel(
    const float* __restrict__ vals, const int* __restrict__ rows,
    const int* __restrict__ cols, int* __restrict__ cursor,
    int2* __restrict__ rec, int4* __restrict__ ovf, int* __restrict__ ovf_cnt)
{
    __shared__ int2 stage[STILE];            // 32 KB, bucket-sorted records
    __shared__ int  hist[N_BUCKET];          // counts, later running cursor
    __shared__ int  lbase[N_BUCKET + 1];     // local exclusive bases
    __shared__ int  gbase[N_BUCKET];         // reserved global bases
    __shared__ int  sscan[2][STHREADS];

    int tid = threadIdx.x;
    int t0 = blockIdx.x * STILE;

    for (int i = tid; i < N_BUCKET; i += STHREADS) hist[i] = 0;
    __syncthreads();

    // pass A: histogram rows (coalesced 4B reads)
    #pragma unroll
    for (int j = 0; j < SEPT; ++j) {
        int e = t0 + j * STHREADS + tid;
        if (e < N_EDGES) atomicAdd(&hist[rows[e] >> RB_LOG], 1);
    }
    __syncthreads();

    // exclusive scan of hist[0..781] -> lbase[0..782]; thread owns chunk of 2
    int c0 = 0, c1 = 0;
    if (2 * tid     < N_BUCKET) c0 = hist[2 * tid];
    if (2 * tid + 1 < N_BUCKET) c1 = hist[2 * tid + 1];
    sscan[0][tid] = c0 + c1;
    __syncthreads();
    int sel = 0;
    for (int off = 1; off < STHREADS; off <<= 1) {
        int x = sscan[sel][tid];
        if (tid >= off) x += sscan[sel][tid - off];
        sscan[1 - sel][tid] = x;
        __syncthreads();
        sel ^= 1;
    }
    int excl = (tid > 0) ? sscan[sel][tid - 1] : 0;
    if (2 * tid     < N_BUCKET) lbase[2 * tid]     = excl;
    if (2 * tid + 1 < N_BUCKET) lbase[2 * tid + 1] = excl + c0;
    if (tid == 0) lbase[N_BUCKET] = sscan[sel][STHREADS - 1];
    __syncthreads();

    // reserve global ranges: ONE atomic per nonempty bucket per tile
    for (int i = tid; i < N_BUCKET; i += STHREADS) {
        int cnt = hist[i];
        gbase[i] = cnt ? atomicAdd(&cursor[i * PAD], cnt) : 0;
    }
    __syncthreads();
    // convert hist -> running local cursor
    for (int i = tid; i < N_BUCKET; i += STHREADS) hist[i] = lbase[i];
    __syncthreads();

    // pass C: re-read edges, place sorted-by-bucket into LDS stage
    #pragma unroll
    for (int j = 0; j < SEPT; ++j) {
        int e = t0 + j * STHREADS + tid;
        if (e < N_EDGES) {
            int r = rows[e], c = cols[e];
            float v = vals[e];
            int bb = r >> RB_LOG;
            int pos = atomicAdd(&hist[bb], 1);
            stage[pos] = make_int2(((r & (ROWS_PER_BUCKET - 1)) << COL_BITS) | c,
                                   __float_as_int(v));
        }
    }
    __syncthreads();

    // pass D: coalesced burst write-out; bucket recovered by binary search
    int ntot = lbase[N_BUCKET];
    for (int i = tid; i < ntot; i += STHREADS) {
        int lo = 0, hi = N_BUCKET;
        while (hi - lo > 1) {
            int mid = (lo + hi) >> 1;
            if (lbase[mid] <= i) lo = mid; else hi = mid;
        }
        int slot = gbase[lo] + (i - lbase[lo]);
        int2 rd = stage[i];
        if (slot < CAP) {
            rec[(size_t)lo * CAP + slot] = rd;
        } else {
            int opos = atomicAdd(ovf_cnt, 1);
            if (opos < OVF_MAX)
                ovf[opos] = make_int4((lo << RB_LOG) | (rd.x >> COL_BITS),
                                      rd.x & COL_MASK, rd.y, 0);
        }
    }
}

// ---------------- gather: sort-free LDS f32 accumulator --------------------
// acc layout [row][c*17+fc]: bank = (4*row + 17*c + fc) % 32 -> per-instr the
// 16 fc lanes span 16 consecutive banks from a row-randomized base (~2-way).
__global__ __launch_bounds__(512) void gather_kernel(
    const float* __restrict__ H, const int2* __restrict__ rec,
    const int* __restrict__ cursor, const int4* __restrict__ ovf,
    const int* __restrict__ ovf_cnt, float* __restrict__ out)
{
    __shared__ float acc[ROWS_PER_BUCKET][68];   // 34.8 KB

    int b = blockIdx.x;
    int tid = threadIdx.x;
    int rg = tid >> 4;       // record slot within round, 0..31
    int fc = tid & 15;       // feature chunk 0..15
    const float4* H4 = reinterpret_cast<const float4*>(H);

    for (int i = tid; i < ROWS_PER_BUCKET * 68; i += 512)
        (&acc[0][0])[i] = 0.f;
    __syncthreads();

    int cnt = min(cursor[b * PAD], CAP);
    const int2* src = rec + (size_t)b * CAP;

    for (int i0 = 0; i0 < cnt; i0 += 32) {
        int rid = i0 + rg;
        if (rid < cnt) {
            int2 r = src[rid];                 // 16 lanes broadcast, 32B/wave
            int row = r.x >> COL_BITS;         // 0..127
            int col = r.x & COL_MASK;
            float v = __int_as_float(r.y);
            float4 h = H4[col * 16 + fc];      // full 256B row per record
            atomicAdd(&acc[row][0 * 17 + fc], v * h.x);
            atomicAdd(&acc[row][1 * 17 + fc], v * h.y);
            atomicAdd(&acc[row][2 * 17 + fc], v * h.z);
            atomicAdd(&acc[row][3 * 17 + fc], v * h.w);
        }
    }
    __syncthreads();

    // ---- overflow records (normally zero) ----
    int novf = min(*ovf_cnt, OVF_MAX);
    int rowbase = b * ROWS_PER_BUCKET;
    for (int i = 0; i < novf; ++i) {
        int4 o = ovf[i];
        int ro = o.x - rowbase;
        if (ro >= 0 && ro < ROWS_PER_BUCKET && (ro & 31) == rg) {
            float4 h = H4[o.y * 16 + fc];
            float v = __int_as_float(o.z);
            atomicAdd(&acc[ro][0 * 17 + fc], v * h.x);
            atomicAdd(&acc[ro][1 * 17 + fc], v * h.y);
            atomicAdd(&acc[ro][2 * 17 + fc], v * h.z);
            atomicAdd(&acc[ro][3 * 17 + fc], v * h.w);
        }
    }
    __syncthreads();

    // ---- coalesced writeback ----
    #pragma unroll
    for (int k = 0; k < 4; ++k) {
        int lrow = k * 32 + rg;
        int row = rowbase + lrow;
        if (row < N_NODES) {
            float4 o4 = make_float4(acc[lrow][0 * 17 + fc],
                                    acc[lrow][1 * 17 + fc],
                                    acc[lrow][2 * 17 + fc],
                                    acc[lrow][3 * 17 + fc]);
            reinterpret_cast<float4*>(out)[row * 16 + fc] = o4;
        }
    }
}

extern "C" void kernel_launch(void* const* d_in, const int* in_sizes, int n_in,
                              void* d_out, int out_size, void* d_ws, size_t ws_size,
                              hipStream_t stream) {
    const float* H    = (const float*)d_in[0];
    const float* vals = (const float*)d_in[1];
    const int*   rows = (const int*)d_in[2];
    const int*   cols = (const int*)d_in[3];
    float* out = (float*)d_out;

    char* ws = (char*)d_ws;
    int2* rec     = (int2*)ws;                         // N_BUCKET*CAP*8B = 16 MB
    int*  cursor  = (int*)(rec + (size_t)N_BUCKET * CAP);  // N_BUCKET*PAD
    int*  ovf_cnt = cursor + N_BUCKET * PAD;           // 16 ints
    int4* ovf     = (int4*)(ovf_cnt + 16);             // OVF_MAX*16B

    hipMemsetAsync(cursor, 0, (N_BUCKET * PAD + 16) * sizeof(int), stream);

    scatter_kernel<<<N_STILE, STHREADS, 0, stream>>>(
        vals, rows, cols, cursor, rec, ovf, ovf_cnt);
    gather_kernel<<<N_BUCKET, 512, 0, stream>>>(H, rec, cursor, ovf, ovf_cnt, out);
}

// Round 3
// 187.272 us; speedup vs baseline: 4.2168x; 4.2168x over previous
//
#include <hip/hip_runtime.h>

#define N_NODES 100000
#define N_EDGES 1600000
#define D_FEAT 64

#define RB_LOG 7
#define ROWS_PER_BUCKET 128
#define N_BUCKET ((N_NODES + ROWS_PER_BUCKET - 1) / ROWS_PER_BUCKET)  // 782

#define COL_BITS 17
#define COL_MASK ((1 << COL_BITS) - 1)

#define CAP 2560       // records per bucket; mean 2048, sigma ~45 -> +11 sigma
#define PAD 16
#define OVF_MAX 4096

// ---------------- scatter: tile counting-sort + coalesced burst write ------
#define STILE 4096
#define STHREADS 512
#define SEPT (STILE / STHREADS)                      // 8
#define N_STILE ((N_EDGES + STILE - 1) / STILE)      // 391

__global__ __launch_bounds__(512) void scatter_kernel(
    const float* __restrict__ vals, const int* __restrict__ rows,
    const int* __restrict__ cols, int* __restrict__ cursor,
    int2* __restrict__ rec, int4* __restrict__ ovf, int* __restrict__ ovf_cnt)
{
    __shared__ int2 stage[STILE];            // 32 KB, bucket-sorted records
    __shared__ int  hist[N_BUCKET];          // counts, later running cursor
    __shared__ int  lbase[N_BUCKET + 1];     // local exclusive bases
    __shared__ int  gbase[N_BUCKET];         // reserved global bases
    __shared__ int  sscan[2][STHREADS];

    int tid = threadIdx.x;
    int t0 = blockIdx.x * STILE;

    for (int i = tid; i < N_BUCKET; i += STHREADS) hist[i] = 0;
    __syncthreads();

    // pass A: load edges into REGISTERS (coalesced) + histogram rows
    int er[SEPT], ec[SEPT], eb[SEPT];
    float ev[SEPT];
    #pragma unroll
    for (int j = 0; j < SEPT; ++j) {
        int e = t0 + j * STHREADS + tid;
        if (e < N_EDGES) {
            er[j] = rows[e]; ec[j] = cols[e]; ev[j] = vals[e];
            eb[j] = er[j] >> RB_LOG;
            atomicAdd(&hist[eb[j]], 1);
        } else {
            eb[j] = -1;
        }
    }
    __syncthreads();

    // exclusive scan of hist[0..781] -> lbase[0..782]; thread owns chunk of 2
    int c0 = 0, c1 = 0;
    if (2 * tid     < N_BUCKET) c0 = hist[2 * tid];
    if (2 * tid + 1 < N_BUCKET) c1 = hist[2 * tid + 1];
    sscan[0][tid] = c0 + c1;
    __syncthreads();
    int sel = 0;
    for (int off = 1; off < STHREADS; off <<= 1) {
        int x = sscan[sel][tid];
        if (tid >= off) x += sscan[sel][tid - off];
        sscan[1 - sel][tid] = x;
        __syncthreads();
        sel ^= 1;
    }
    int excl = (tid > 0) ? sscan[sel][tid - 1] : 0;
    if (2 * tid     < N_BUCKET) lbase[2 * tid]     = excl;
    if (2 * tid + 1 < N_BUCKET) lbase[2 * tid + 1] = excl + c0;
    if (tid == 0) lbase[N_BUCKET] = sscan[sel][STHREADS - 1];
    __syncthreads();

    // reserve global ranges: ONE atomic per nonempty bucket per tile
    for (int i = tid; i < N_BUCKET; i += STHREADS) {
        int cnt = hist[i];
        gbase[i] = cnt ? atomicAdd(&cursor[i * PAD], cnt) : 0;
    }
    __syncthreads();
    // convert hist -> running local cursor
    for (int i = tid; i < N_BUCKET; i += STHREADS) hist[i] = lbase[i];
    __syncthreads();

    // pass C: place records (from registers) sorted-by-bucket into LDS stage
    #pragma unroll
    for (int j = 0; j < SEPT; ++j) {
        if (eb[j] >= 0) {
            int pos = atomicAdd(&hist[eb[j]], 1);
            stage[pos] = make_int2(
                ((er[j] & (ROWS_PER_BUCKET - 1)) << COL_BITS) | ec[j],
                __float_as_int(ev[j]));
        }
    }
    __syncthreads();

    // pass D: coalesced burst write-out; bucket recovered by binary search
    int ntot = lbase[N_BUCKET];
    for (int i = tid; i < ntot; i += STHREADS) {
        int lo = 0, hi = N_BUCKET;
        while (hi - lo > 1) {
            int mid = (lo + hi) >> 1;
            if (lbase[mid] <= i) lo = mid; else hi = mid;
        }
        int slot = gbase[lo] + (i - lbase[lo]);
        int2 rd = stage[i];
        if (slot < CAP) {
            rec[(size_t)lo * CAP + slot] = rd;
        } else {
            int opos = atomicAdd(ovf_cnt, 1);
            if (opos < OVF_MAX)
                ovf[opos] = make_int4((lo << RB_LOG) | (rd.x >> COL_BITS),
                                      rd.x & COL_MASK, rd.y, 0);
        }
    }
}

// ---- gather: reg-staged counting sort + register accumulate, 8 lanes/rec --
// rec read ONCE (staged in registers while counting); accumulate uses 8 lanes
// per record with 2 float4 loads each -> 2x per-wave outstanding loads vs r1.
#define HELD 5   // ceil(CAP / 512)

__global__ __launch_bounds__(512) void gather_kernel(
    const float* __restrict__ H, const int2* __restrict__ rec,
    const int* __restrict__ cursor, const int4* __restrict__ ovf,
    const int* __restrict__ ovf_cnt, float* __restrict__ out)
{
    __shared__ int2 recbuf[CAP];                 // 20 KB, row-sorted
    __shared__ int  rstart[ROWS_PER_BUCKET + 1];
    __shared__ int  rcur[ROWS_PER_BUCKET];
    __shared__ int  sbuf[2][ROWS_PER_BUCKET];

    int b = blockIdx.x;
    int tid = threadIdx.x;
    int rg = tid >> 3;       // 0..63 : owns rows rg and rg+64
    int fc = tid & 7;        // 0..7  : float4 chunks fc and fc+8
    const float4* H4 = reinterpret_cast<const float4*>(H);

    if (tid < ROWS_PER_BUCKET) rcur[tid] = 0;
    __syncthreads();

    int cnt = min(cursor[b * PAD], CAP);
    const int2* src = rec + (size_t)b * CAP;

    // ---- single global pass: stage records in registers + count rows ----
    int2 held[HELD];
    #pragma unroll
    for (int h = 0; h < HELD; ++h) {
        int i = tid + h * 512;
        if (i < cnt) {
            int2 r = src[i];
            held[h] = r;
            atomicAdd(&rcur[r.x >> COL_BITS], 1);
        }
    }
    __syncthreads();

    // ---- scan 128 counts -> rstart ----
    if (tid < ROWS_PER_BUCKET) sbuf[0][tid] = rcur[tid];
    __syncthreads();
    int sel = 0;
    for (int off = 1; off < ROWS_PER_BUCKET; off <<= 1) {
        if (tid < ROWS_PER_BUCKET) {
            int x = sbuf[sel][tid];
            if (tid >= off) x += sbuf[sel][tid - off];
            sbuf[1 - sel][tid] = x;
        }
        __syncthreads();
        sel ^= 1;
    }
    if (tid < ROWS_PER_BUCKET) rstart[tid + 1] = sbuf[sel][tid];
    if (tid == 0) rstart[0] = 0;
    __syncthreads();
    if (tid < ROWS_PER_BUCKET) rcur[tid] = rstart[tid];
    __syncthreads();

    // ---- place held records sorted-by-row into recbuf ----
    #pragma unroll
    for (int h = 0; h < HELD; ++h) {
        int i = tid + h * 512;
        if (i < cnt) {
            int2 r = held[h];
            int pos = atomicAdd(&rcur[r.x >> COL_BITS], 1);
            recbuf[pos] = r;
        }
    }
    __syncthreads();

    // ---- register-accumulate: rows rg (k=0) and rg+64 (k=1) ----
    float4 accA[2], accB[2];   // chunks fc and fc+8 of each owned row
    #pragma unroll
    for (int k = 0; k < 2; ++k) {
        accA[k] = make_float4(0.f, 0.f, 0.f, 0.f);
        accB[k] = make_float4(0.f, 0.f, 0.f, 0.f);
    }

    #pragma unroll
    for (int k = 0; k < 2; ++k) {
        int ro = k * 64 + rg;
        int s = rstart[ro], e2 = rstart[ro + 1];
        int i = s;
        for (; i + 4 <= e2; i += 4) {
            int2 r0 = recbuf[i];
            int2 r1 = recbuf[i + 1];
            int2 r2 = recbuf[i + 2];
            int2 r3 = recbuf[i + 3];
            int c0b = (r0.x & COL_MASK) * 16, c1b = (r1.x & COL_MASK) * 16;
            int c2b = (r2.x & COL_MASK) * 16, c3b = (r3.x & COL_MASK) * 16;
            float4 a0 = H4[c0b + fc],     a1 = H4[c1b + fc];
            float4 a2 = H4[c2b + fc],     a3 = H4[c3b + fc];
            float4 b0 = H4[c0b + 8 + fc], b1 = H4[c1b + 8 + fc];
            float4 b2 = H4[c2b + 8 + fc], b3 = H4[c3b + 8 + fc];
            float v0 = __int_as_float(r0.y), v1 = __int_as_float(r1.y);
            float v2 = __int_as_float(r2.y), v3 = __int_as_float(r3.y);
            accA[k].x += v0 * a0.x; accA[k].y += v0 * a0.y;
            accA[k].z += v0 * a0.z; accA[k].w += v0 * a0.w;
            accB[k].x += v0 * b0.x; accB[k].y += v0 * b0.y;
            accB[k].z += v0 * b0.z; accB[k].w += v0 * b0.w;
            accA[k].x += v1 * a1.x; accA[k].y += v1 * a1.y;
            accA[k].z += v1 * a1.z; accA[k].w += v1 * a1.w;
            accB[k].x += v1 * b1.x; accB[k].y += v1 * b1.y;
            accB[k].z += v1 * b1.z; accB[k].w += v1 * b1.w;
            accA[k].x += v2 * a2.x; accA[k].y += v2 * a2.y;
            accA[k].z += v2 * a2.z; accA[k].w += v2 * a2.w;
            accB[k].x += v2 * b2.x; accB[k].y += v2 * b2.y;
            accB[k].z += v2 * b2.z; accB[k].w += v2 * b2.w;
            accA[k].x += v3 * a3.x; accA[k].y += v3 * a3.y;
            accA[k].z += v3 * a3.z; accA[k].w += v3 * a3.w;
            accB[k].x += v3 * b3.x; accB[k].y += v3 * b3.y;
            accB[k].z += v3 * b3.z; accB[k].w += v3 * b3.w;
        }
        for (; i < e2; ++i) {
            int2 r0 = recbuf[i];
            int c0b = (r0.x & COL_MASK) * 16;
            float4 a0 = H4[c0b + fc];
            float4 b0 = H4[c0b + 8 + fc];
            float v0 = __int_as_float(r0.y);
            accA[k].x += v0 * a0.x; accA[k].y += v0 * a0.y;
            accA[k].z += v0 * a0.z; accA[k].w += v0 * a0.w;
            accB[k].x += v0 * b0.x; accB[k].y += v0 * b0.y;
            accB[k].z += v0 * b0.z; accB[k].w += v0 * b0.w;
        }
    }

    // ---- overflow records (normally zero) ----
    int novf = min(*ovf_cnt, OVF_MAX);
    int rowbase = b * ROWS_PER_BUCKET;
    for (int i = 0; i < novf; ++i) {
        int4 o = ovf[i];
        int ro = o.x - rowbase;
        if (ro >= 0 && ro < ROWS_PER_BUCKET && (ro & 63) == rg) {
            int k = ro >> 6;
            float4 a = H4[o.y * 16 + fc];
            float4 bq = H4[o.y * 16 + 8 + fc];
            float v = __int_as_float(o.z);
            accA[k].x += v * a.x;  accA[k].y += v * a.y;
            accA[k].z += v * a.z;  accA[k].w += v * a.w;
            accB[k].x += v * bq.x; accB[k].y += v * bq.y;
            accB[k].z += v * bq.z; accB[k].w += v * bq.w;
        }
    }

    // ---- coalesced writeback, exactly once ----
    #pragma unroll
    for (int k = 0; k < 2; ++k) {
        int row = rowbase + k * 64 + rg;
        if (row < N_NODES) {
            reinterpret_cast<float4*>(out)[row * 16 + fc]     = accA[k];
            reinterpret_cast<float4*>(out)[row * 16 + 8 + fc] = accB[k];
        }
    }
}

extern "C" void kernel_launch(void* const* d_in, const int* in_sizes, int n_in,
                              void* d_out, int out_size, void* d_ws, size_t ws_size,
                              hipStream_t stream) {
    const float* H    = (const float*)d_in[0];
    const float* vals = (const float*)d_in[1];
    const int*   rows = (const int*)d_in[2];
    const int*   cols = (const int*)d_in[3];
    float* out = (float*)d_out;

    char* ws = (char*)d_ws;
    int2* rec     = (int2*)ws;                             // N_BUCKET*CAP*8B = 16 MB
    int*  cursor  = (int*)(rec + (size_t)N_BUCKET * CAP);  // N_BUCKET*PAD
    int*  ovf_cnt = cursor + N_BUCKET * PAD;               // 16 ints
    int4* ovf     = (int4*)(ovf_cnt + 16);                 // OVF_MAX*16B

    hipMemsetAsync(cursor, 0, (N_BUCKET * PAD + 16) * sizeof(int), stream);

    scatter_kernel<<<N_STILE, STHREADS, 0, stream>>>(
        vals, rows, cols, cursor, rec, ovf, ovf_cnt);
    gather_kernel<<<N_BUCKET, 512, 0, stream>>>(H, rec, cursor, ovf, ovf_cnt, out);
}